// Round 1
// 2480.026 us; speedup vs baseline: 2.1282x; 2.1282x over previous
//
#include <hip/hip_runtime.h>
#include <hip/hip_bf16.h>

// Problem: T=256, B=32, VOCAB=32000, EMB=256, LAT=512, OUT=32000
// d_out = [outputs (8192 x 32000) f32][hidden (8192 x 512) f32]

#define T_STEPS 256
#define BATCH 32
#define EMB 256
#define LAT 512
#define NOUT 32000
#define MROWS 8192  // T*B

#define GPB 4    // blocks (groups) per chain
#define OSL 128  // output slice per block (LAT / GPB)

typedef __attribute__((ext_vector_type(8))) short bf16x8;
typedef __attribute__((ext_vector_type(4))) float f32x4;

// ---------------------------------------------------------------------------
// Kernel T: W_o [512][32000] f32  ->  W_oT [32000][512] bf16
// ---------------------------------------------------------------------------
__global__ __launch_bounds__(256) void transpose_wo(
    const float* __restrict__ Wo, __hip_bfloat16* __restrict__ WoT) {
  __shared__ float tile[32][33];
  const int n0 = blockIdx.x * 32;  // 1000 blocks over N
  const int k0 = blockIdx.y * 32;  // 16 blocks over K
  const int c = threadIdx.x & 31;
  const int r0 = threadIdx.x >> 5;  // 0..7
#pragma unroll
  for (int rr = r0; rr < 32; rr += 8)
    tile[rr][c] = Wo[(size_t)(k0 + rr) * NOUT + n0 + c];
  __syncthreads();
#pragma unroll
  for (int rr = r0; rr < 32; rr += 8)
    WoT[(size_t)(n0 + rr) * LAT + k0 + c] = __float2bfloat16(tile[c][rr]);
}

// ---------------------------------------------------------------------------
// Kernel 1: xproj[m][o] = sum_k emb[x[m]][k] * W_h[k][o] + b_h[o]
// grid 512 blocks x 256 thr, 16 rows per block
// ---------------------------------------------------------------------------
__global__ __launch_bounds__(256) void xproj_kernel(
    const int* __restrict__ x, const float* __restrict__ emb,
    const float* __restrict__ W_h, const float* __restrict__ b_h,
    float* __restrict__ xproj) {
  __shared__ float xe[16][EMB];
  const int m0 = blockIdx.x * 16;
  // stage gathered embedding rows (16 x 256 f32 = 1024 float4)
#pragma unroll
  for (int j = 0; j < 4; ++j) {
    int idx = threadIdx.x + j * 256;  // float4 index
    int r = idx >> 6;                 // 64 float4 per row
    int c4 = idx & 63;
    int tok = x[m0 + r];
    ((float4*)xe[r])[c4] = ((const float4*)(emb + (size_t)tok * EMB))[c4];
  }
  __syncthreads();

  const int c = threadIdx.x;  // col c and c+256
  float accA[16], accB[16];
#pragma unroll
  for (int r = 0; r < 16; ++r) { accA[r] = 0.f; accB[r] = 0.f; }
  for (int k = 0; k < EMB; ++k) {
    float wa = W_h[(size_t)k * LAT + c];
    float wb = W_h[(size_t)k * LAT + c + 256];
#pragma unroll
    for (int r = 0; r < 16; ++r) {
      float xv = xe[r][k];
      accA[r] = fmaf(xv, wa, accA[r]);
      accB[r] = fmaf(xv, wb, accB[r]);
    }
  }
  const float ba = b_h[c], bb = b_h[c + 256];
#pragma unroll
  for (int r = 0; r < 16; ++r) {
    xproj[(size_t)(m0 + r) * LAT + c] = accA[r] + ba;
    xproj[(size_t)(m0 + r) * LAT + c + 256] = accB[r] + bb;
  }
}

// ---------------------------------------------------------------------------
// Kernel 2: recurrent scan, 4-way chain-split across CUs.
//
// Grid (32 chains x 4 groups) = 128 blocks x 512 threads, 1 block/CU.
// Block (c,g) owns outputs [g*128, g*128+128) of chain c; its 128x512 f32
// weight slice (256 KB) is register-resident: thread (oloc=t>>2, kq=t&3)
// holds W_hh[kq*128 .. kq*128+128)[og] = 32 float4 = 128 VGPRs.
// (The old 1-block-per-chain version needed 256 f32/thread at a 128-VGPR
//  cap -> spilled to scratch -> 14.8 us/step of pure reload latency.)
//
// Per-step protocol (device-scope, XCD-safe):
//   wait flags[c][t-1]==4  ->  load h_{t-1} (agent-scope sc1 loads) -> LDS
//   -> 128 FMAs + quad shfl-reduce -> relu -> publish slice via agent-scope
//   stores -> __syncthreads (drains vmcnt) -> flags[c][t] += 1 (release).
// Ping-pong h buffer is safe: flag t-1 == 4 implies every sibling finished
// READING buffer (t-2)&1 == (t)&1 before we overwrite it.
// 128 blocks <= 256 CUs => all co-resident, spin cannot deadlock.
// ---------------------------------------------------------------------------
__global__ __launch_bounds__(512, 2) void rnn_scan(
    const float* __restrict__ W_h, const float* __restrict__ xproj,
    float* __restrict__ hidden_out, __hip_bfloat16* __restrict__ hidden_bf,
    float* hexch, int* flags) {
  const int c = blockIdx.x;    // chain 0..31
  const int g = blockIdx.y;    // group 0..3
  const int tid = threadIdx.x; // 0..511
  const int oloc = tid >> 2;   // 0..127
  const int kq = tid & 3;      // K-quarter, range [kq*128, kq*128+128)
  const int og = g * OSL + oloc;
  const float* Whh = W_h + (size_t)EMB * LAT;  // [512][512]

  // one-time weight load: rows kq*128+4j+r, column og
  float4 w[32];
#pragma unroll
  for (int j = 0; j < 32; ++j) {
    const size_t kb = (size_t)(kq * 128 + 4 * j);
    w[j].x = Whh[(kb + 0) * LAT + og];
    w[j].y = Whh[(kb + 1) * LAT + og];
    w[j].z = Whh[(kb + 2) * LAT + og];
    w[j].w = Whh[(kb + 3) * LAT + og];
  }

  // h staging buffer, padded +4 floats per 128-float segment so the four
  // kq groups' ds_read_b128 hit distinct banks (k stored at k + (k>>7)*4)
  __shared__ float hs[LAT + 16];
  float* hx = hexch + (size_t)c * 2 * LAT;
  int* flg = flags + c * T_STEPS;

  for (int step = 0; step < T_STEPS; ++step) {
    const size_t rm = (size_t)step * BATCH + c;
    // prefetch xproj before the wait (latency hides under the spin/barrier)
    float xp = 0.f;
    if (kq == 0) xp = xproj[rm * LAT + og];

    if (step == 0) {
      hs[tid + ((tid >> 7) << 2)] = 0.f;  // h0 = 0
    } else {
      if (tid == 0) {
        while (__hip_atomic_load(&flg[step - 1], __ATOMIC_RELAXED,
                                 __HIP_MEMORY_SCOPE_AGENT) < GPB) {}
      }
      __syncthreads();
      // agent-scope (sc1) load: fresh from coherence point across XCDs
      const float hv =
          __hip_atomic_load(&hx[((step - 1) & 1) * LAT + tid],
                            __ATOMIC_RELAXED, __HIP_MEMORY_SCOPE_AGENT);
      hs[tid + ((tid >> 7) << 2)] = hv;
    }
    __syncthreads();

    const float4* h4 = (const float4*)(hs + kq * 132);  // 528 B = 16B-aligned
    float ax = 0.f, ay = 0.f, az = 0.f, aw = 0.f;
#pragma unroll
    for (int j = 0; j < 32; ++j) {
      const float4 hv = h4[j];
      ax = fmaf(hv.x, w[j].x, ax);
      ay = fmaf(hv.y, w[j].y, ay);
      az = fmaf(hv.z, w[j].z, az);
      aw = fmaf(hv.w, w[j].w, aw);
    }
    float acc = (ax + ay) + (az + aw);
    acc += __shfl_xor(acc, 1);  // combine the four K-quarters (lane quad)
    acc += __shfl_xor(acc, 2);

    float val = 0.f;
    if (kq == 0) {
      val = fmaxf(xp + acc, 0.f);
      __hip_atomic_store(&hx[(step & 1) * LAT + og], val, __ATOMIC_RELAXED,
                         __HIP_MEMORY_SCOPE_AGENT);
    }
    __syncthreads();  // barrier drains vmcnt: all hx stores are complete
    if (tid == 0)
      __hip_atomic_fetch_add(&flg[step], 1, __ATOMIC_RELEASE,
                             __HIP_MEMORY_SCOPE_AGENT);
    // off the critical path: persist hidden state (drains at next barrier)
    if (kq == 0) {
      hidden_out[rm * LAT + og] = val;
      hidden_bf[rm * LAT + og] = __float2bfloat16(val);
    }
  }
}

// ---------------------------------------------------------------------------
// Kernel 3: outputs = hidden(bf16) @ W_o(bf16, pre-transposed) + b_o  (f32 out)
// 128x128 tile, BK=64, 256 thr (4 waves, each 64x64 = 4x4 MFMA tiles),
// global_load_lds width-16 staging, mfma_f32_16x16x32_bf16.
// ---------------------------------------------------------------------------
__global__ __launch_bounds__(256, 2) void gemm_out(
    const __hip_bfloat16* __restrict__ A,   // [8192][512] bf16
    const __hip_bfloat16* __restrict__ Bt,  // [32000][512] bf16
    const float* __restrict__ bias,         // [32000]
    float* __restrict__ C) {                // [8192][32000] f32
  __shared__ short As[128 * 64];
  __shared__ short Bs[128 * 64];
  const int tid = threadIdx.x;
  const int n0 = blockIdx.x * 128;  // 250
  const int m0 = blockIdx.y * 128;  // 64
  const int w = tid >> 6;
  const int lane = tid & 63;
  const int wm = (w & 1) * 64;
  const int wn = (w >> 1) * 64;
  const int q = lane >> 4;
  const int m16 = lane & 15;

  f32x4 acc[4][4] = {};

  for (int kt = 0; kt < 8; ++kt) {
    const int k0 = kt * 64;
    __syncthreads();  // LDS free to overwrite
#pragma unroll
    for (int j = 0; j < 4; ++j) {
      int e = j * 256 + tid;  // 0..1023, 16B chunk id
      int row = e >> 3;       // 8 chunks (128B) per row of 64 bf16
      int ch = e & 7;
      __builtin_amdgcn_global_load_lds(
          (const __attribute__((address_space(1))) void*)(A + (size_t)(m0 + row) * LAT + k0 + ch * 8),
          (__attribute__((address_space(3))) void*)(As + (size_t)e * 8), 16, 0, 0);
      __builtin_amdgcn_global_load_lds(
          (const __attribute__((address_space(1))) void*)(Bt + (size_t)(n0 + row) * LAT + k0 + ch * 8),
          (__attribute__((address_space(3))) void*)(Bs + (size_t)e * 8), 16, 0, 0);
    }
    __syncthreads();  // staging complete (vmcnt drained by barrier)
#pragma unroll
    for (int kk = 0; kk < 2; ++kk) {
      bf16x8 af[4], bfr[4];
#pragma unroll
      for (int i = 0; i < 4; ++i) {
        af[i] = *(const bf16x8*)(As + (wm + i * 16 + m16) * 64 + kk * 32 + q * 8);
        bfr[i] = *(const bf16x8*)(Bs + (wn + i * 16 + m16) * 64 + kk * 32 + q * 8);
      }
#pragma unroll
      for (int mt = 0; mt < 4; ++mt)
#pragma unroll
        for (int nt = 0; nt < 4; ++nt)
          acc[mt][nt] = __builtin_amdgcn_mfma_f32_16x16x32_bf16(
              af[mt], bfr[nt], acc[mt][nt], 0, 0, 0);
    }
  }

  // epilogue: C/D layout col = lane&15, row = q*4 + r
#pragma unroll
  for (int nt = 0; nt < 4; ++nt) {
    const int col = n0 + wn + nt * 16 + m16;
    const float bv = bias[col];
#pragma unroll
    for (int mt = 0; mt < 4; ++mt) {
      const int rbase = m0 + wm + mt * 16 + q * 4;
#pragma unroll
      for (int r = 0; r < 4; ++r)
        C[(size_t)(rbase + r) * NOUT + col] = acc[mt][nt][r] + bv;
    }
  }
}

// ---------------------------------------------------------------------------
extern "C" void kernel_launch(void* const* d_in, const int* in_sizes, int n_in,
                              void* d_out, int out_size, void* d_ws, size_t ws_size,
                              hipStream_t stream) {
  const int* x = (const int*)d_in[0];
  const float* emb = (const float*)d_in[1];
  const float* W_h = (const float*)d_in[2];
  const float* b_h = (const float*)d_in[3];
  const float* W_o = (const float*)d_in[4];
  const float* b_o = (const float*)d_in[5];

  float* outputs = (float*)d_out;                         // 8192*32000
  float* hidden = outputs + (size_t)MROWS * NOUT;         // 8192*512

  char* ws = (char*)d_ws;
  __hip_bfloat16* WoT = (__hip_bfloat16*)ws;                          // 32,768,000 B
  float* xproj = (float*)(ws + 32768000);                             // 16,777,216 B
  __hip_bfloat16* hid_bf = (__hip_bfloat16*)(ws + 32768000 + 16777216);  // 8,388,608 B

  // scan-time scratch carved from the outputs region of d_out (gemm_out
  // overwrites it afterwards, stream-ordered): hexch 32x2x512 f32, then flags
  float* hexch = outputs;
  int* flags = (int*)(outputs + (size_t)2 * BATCH * LAT);  // 32*256 ints

  hipMemsetAsync(flags, 0, (size_t)BATCH * T_STEPS * sizeof(int), stream);
  transpose_wo<<<dim3(1000, 16), 256, 0, stream>>>(W_o, WoT);
  xproj_kernel<<<512, 256, 0, stream>>>(x, emb, W_h, b_h, xproj);
  rnn_scan<<<dim3(BATCH, GPB), 512, 0, stream>>>(W_h, xproj, hidden, hid_bf,
                                                 hexch, flags);
  gemm_out<<<dim3(250, 64), 256, 0, stream>>>(hid_bf, WoT, b_o, outputs);
}